// Round 1
// baseline (121.542 us; speedup 1.0000x reference)
//
#include <hip/hip_runtime.h>

// Pairwise clipped-linear loss:
//   d2_ij = |x_i|^2 + |x_j|^2 - 2 x_i.x_j ;  f(d) = (d-1)(1-d/2) for d<2 else 0
//   out = 0.25 * sum_ij f(d_ij)
// x layout: [C=32][N=8192] fp32 (channel-major, contiguous in point index).

constexpr int N  = 8192;
constexpr int CH = 32;
constexpr int BT = 128;   // point-tile edge

__global__ __launch_bounds__(256) void pair_loss_kernel(const float* __restrict__ x,
                                                        float* __restrict__ out) {
    const int bi = blockIdx.y;
    const int bj = blockIdx.x;
    if (bj < bi) return;                    // triangular symmetry: skip lower blocks

    __shared__ alignas(16) float As[CH][BT];
    __shared__ alignas(16) float Bs[CH][BT];
    __shared__ alignas(16) float sqA[BT];
    __shared__ alignas(16) float sqB[BT];
    __shared__ float wsum[4];

    const int t  = threadIdx.x;
    const int i0 = bi * BT;
    const int j0 = bj * BT;

    // ---- stage tiles: 32x128 floats each; consecutive t -> consecutive n (coalesced)
    #pragma unroll
    for (int r = 0; r < 16; ++r) {
        const int idx = r * 256 + t;        // 0..4095
        const int c   = idx >> 7;
        const int p   = idx & 127;
        As[c][p] = x[c * N + i0 + p];
        Bs[c][p] = x[c * N + j0 + p];
    }
    __syncthreads();

    // ---- per-point squared norms, SAME fma order as the dot loop below so that
    // the diagonal d2 cancels bitwise to exactly 0.
    if (t < BT) {
        float s = 0.f;
        #pragma unroll
        for (int c = 0; c < CH; ++c) { const float a = As[c][t]; s = fmaf(a, a, s); }
        sqA[t] = s;
    } else {
        const int p = t - BT;
        float s = 0.f;
        #pragma unroll
        for (int c = 0; c < CH; ++c) { const float b = Bs[c][p]; s = fmaf(b, b, s); }
        sqB[p] = s;
    }
    __syncthreads();

    // ---- 16x16 thread layout, 8x8 microtile split as {base, base+64} so each
    // operand read is a float4 and lane addresses cover all 32 banks (<=2-way).
    const int tx = t & 15;
    const int ty = t >> 4;
    const int ra = ty * 4;                  // rows: ra..ra+3, ra+64..ra+67
    const int cb = tx * 4;                  // cols: cb..cb+3, cb+64..cb+67

    float acc[8][8];
    #pragma unroll
    for (int u = 0; u < 8; ++u)
        #pragma unroll
        for (int v = 0; v < 8; ++v) acc[u][v] = 0.f;

    #pragma unroll
    for (int c = 0; c < CH; ++c) {
        const float4 a0 = *(const float4*)&As[c][ra];
        const float4 a1 = *(const float4*)&As[c][ra + 64];
        const float4 b0 = *(const float4*)&Bs[c][cb];
        const float4 b1 = *(const float4*)&Bs[c][cb + 64];
        const float a[8] = {a0.x, a0.y, a0.z, a0.w, a1.x, a1.y, a1.z, a1.w};
        const float b[8] = {b0.x, b0.y, b0.z, b0.w, b1.x, b1.y, b1.z, b1.w};
        #pragma unroll
        for (int u = 0; u < 8; ++u)
            #pragma unroll
            for (int v = 0; v < 8; ++v)
                acc[u][v] = fmaf(a[u], b[v], acc[u][v]);
    }

    // ---- epilogue: d2 -> f(d), accumulate
    const float4 s0 = *(const float4*)&sqA[ra];
    const float4 s1 = *(const float4*)&sqA[ra + 64];
    const float4 t0 = *(const float4*)&sqB[cb];
    const float4 t1 = *(const float4*)&sqB[cb + 64];
    const float sa[8] = {s0.x, s0.y, s0.z, s0.w, s1.x, s1.y, s1.z, s1.w};
    const float sb[8] = {t0.x, t0.y, t0.z, t0.w, t1.x, t1.y, t1.z, t1.w};

    float lsum = 0.f;
    #pragma unroll
    for (int u = 0; u < 8; ++u) {
        #pragma unroll
        for (int v = 0; v < 8; ++v) {
            float d2 = sa[u] + sb[v] - 2.f * acc[u][v];
            if (d2 < 4.f) {                 // rare off-diagonal; wave-coherent skip
                d2 = fmaxf(d2, 0.f);
                const float d = sqrtf(d2);
                lsum += (d - 1.f) * (1.f - 0.5f * d);
            }
        }
    }

    // ---- block reduction -> one atomic per block
    #pragma unroll
    for (int off = 32; off > 0; off >>= 1)
        lsum += __shfl_down(lsum, off, 64);
    if ((t & 63) == 0) wsum[t >> 6] = lsum;
    __syncthreads();
    if (t == 0) {
        const float s = wsum[0] + wsum[1] + wsum[2] + wsum[3];
        const float scale = (bi == bj) ? 0.25f : 0.5f;   // off-diag blocks count twice
        atomicAdd(out, s * scale);
    }
}

extern "C" void kernel_launch(void* const* d_in, const int* in_sizes, int n_in,
                              void* d_out, int out_size, void* d_ws, size_t ws_size,
                              hipStream_t stream) {
    const float* x  = (const float*)d_in[0];
    float* out      = (float*)d_out;
    hipMemsetAsync(out, 0, sizeof(float), stream);   // d_out is poisoned 0xAA
    dim3 grid(N / BT, N / BT);
    pair_loss_kernel<<<grid, 256, 0, stream>>>(x, out);
}

// Round 2
// 84.257 us; speedup vs baseline: 1.4425x; 1.4425x over previous
//
#include <hip/hip_runtime.h>

// Pairwise clipped-linear loss via f16 MFMA Gram matrix.
//   d2_ij = sq_i + sq_j - 2*g_ij,  g = X^T X  (K=C=32)
//   f(d) = (d-1)(1-d/2) for d<2 else 0 ; out = 0.25 * sum_ij f(d_ij)
// Diagonal (i==j) handled analytically: 8192 * f(0) * 0.25 = -2048 exactly
// (f16 MFMA g_ii would not cancel sq_i bitwise; threshold is loose but the
//  diagonal error would be ~900 — must be exact).
// Off-diagonal: nearest pair has d2 >> 4 (chi^2_32 concentration; R1 fp32 run
// confirmed absmax 0.0), f16 perturbs d2 by ~1e-2 near the continuous cutoff.

constexpr int N  = 8192;
constexpr int CH = 32;
constexpr int BT = 128;   // block tile edge

typedef _Float16 f16x8 __attribute__((ext_vector_type(8)));
typedef float    f32x16 __attribute__((ext_vector_type(16)));
typedef float    f32x4  __attribute__((ext_vector_type(4)));

// x fp32 [CH][N]  ->  xT f16 [N][CH] (A/B operand feed) + sq fp32 [N]
__global__ __launch_bounds__(256) void prep_kernel(const float* __restrict__ x,
                                                   _Float16* __restrict__ xT,
                                                   float* __restrict__ sq) {
    const int n = blockIdx.x * 256 + threadIdx.x;
    float s = 0.f;
    union { _Float16 h[CH]; uint4 q[4]; } u;
    #pragma unroll
    for (int c = 0; c < CH; ++c) {
        const float v = x[c * N + n];      // coalesced: lanes read consecutive n
        s = fmaf(v, v, s);
        u.h[c] = (_Float16)v;              // RNE
    }
    sq[n] = s;
    uint4* dst = (uint4*)(xT + (size_t)n * CH);
    #pragma unroll
    for (int r = 0; r < 4; ++r) dst[r] = u.q[r];
}

// 128x128 tile per block, 4 waves in 2x2 quadrants of 64x64, each wave owns
// 2x2 tiles of 32x32 -> 8x mfma_f32_32x32x16_f16 (K=32 = 2 steps).
// A-frag layout (32x32x16): element A[m][k] at lane m=(l&31), k=(l>>5)*8+j.
// C/D layout (32x32): col = lane&31, row = (r&3) + 8*(r>>2) + 4*(lane>>5).
__global__ __launch_bounds__(256) void pair_loss_mfma(const _Float16* __restrict__ xT,
                                                      const float* __restrict__ sq,
                                                      float* __restrict__ out) {
    const int bi = blockIdx.y, bj = blockIdx.x;
    if (bj < bi) return;                    // triangular symmetry
    const int i0 = bi * BT, j0 = bj * BT;
    const int t    = threadIdx.x;
    const int lane = t & 63, w = t >> 6;
    const int qr = w >> 1, qc = w & 1;      // wave quadrant in the 128x128 tile
    const int l31 = lane & 31;
    const int lh  = lane >> 5;

    __shared__ alignas(16) float sqi_s[BT];
    __shared__ alignas(16) float sqj_s[BT];
    __shared__ float wsum[4];

    if (t < BT) sqi_s[t]      = sq[i0 + t];
    else        sqj_s[t - BT] = sq[j0 + t - BT];

    // ---- operand fragments straight from global (512 KB total, L2-resident)
    f16x8 Af[2][2], Bf[2][2];               // [point-tile][k-half]
    #pragma unroll
    for (int rt = 0; rt < 2; ++rt)
        #pragma unroll
        for (int kh = 0; kh < 2; ++kh) {
            const int arow = i0 + qr * 64 + rt * 32 + l31;
            const int brow = j0 + qc * 64 + rt * 32 + l31;
            const int koff = kh * 16 + lh * 8;
            Af[rt][kh] = *(const f16x8*)(xT + (size_t)arow * CH + koff);
            Bf[rt][kh] = *(const f16x8*)(xT + (size_t)brow * CH + koff);
        }

    f32x16 acc[2][2];
    #pragma unroll
    for (int rt = 0; rt < 2; ++rt)
        #pragma unroll
        for (int ct = 0; ct < 2; ++ct)
            #pragma unroll
            for (int r = 0; r < 16; ++r) acc[rt][ct][r] = 0.f;

    #pragma unroll
    for (int rt = 0; rt < 2; ++rt)
        #pragma unroll
        for (int ct = 0; ct < 2; ++ct) {
            acc[rt][ct] = __builtin_amdgcn_mfma_f32_32x32x16_f16(Af[rt][0], Bf[ct][0], acc[rt][ct], 0, 0, 0);
            acc[rt][ct] = __builtin_amdgcn_mfma_f32_32x32x16_f16(Af[rt][1], Bf[ct][1], acc[rt][ct], 0, 0, 0);
        }

    __syncthreads();                        // sq tiles visible in LDS

    // ---- epilogue: d2 -> f(d); wave-coherent skip (d2 >= 4 for ~all pairs)
    const bool diagblk = (bi == bj);
    float lsum = 0.f;
    #pragma unroll
    for (int rt = 0; rt < 2; ++rt) {
        const int rbase = qr * 64 + rt * 32 + 4 * lh;
        f32x4 sr[4];                        // 16 row norms as 4x ds_read_b128
        #pragma unroll
        for (int g4 = 0; g4 < 4; ++g4) sr[g4] = *(const f32x4*)&sqi_s[rbase + g4 * 8];
        #pragma unroll
        for (int ct = 0; ct < 2; ++ct) {
            const int cloc = qc * 64 + ct * 32 + l31;
            const float sc = sqj_s[cloc];
            #pragma unroll
            for (int r = 0; r < 16; ++r) {
                const float g   = acc[rt][ct][r];
                const int rloc  = rbase + (r & 3) + 8 * (r >> 2);
                float d2 = sr[r >> 2][r & 3] + sc - 2.f * g;
                const bool diag = diagblk && (rloc == cloc);   // true diagonal: analytic
                if (d2 < 4.f && !diag) {
                    d2 = fmaxf(d2, 0.f);
                    const float d = sqrtf(d2);
                    lsum += (d - 1.f) * (1.f - 0.5f * d);
                }
            }
        }
    }

    // ---- reduce: wave shuffle -> LDS -> one atomic per block
    #pragma unroll
    for (int off = 32; off > 0; off >>= 1) lsum += __shfl_down(lsum, off, 64);
    if ((t & 63) == 0) wsum[t >> 6] = lsum;
    __syncthreads();
    if (t == 0) {
        const float s = wsum[0] + wsum[1] + wsum[2] + wsum[3];
        if (s != 0.f) atomicAdd(out, s * (diagblk ? 0.25f : 0.5f));
        if (bi == 0 && bj == 0) atomicAdd(out, -0.25f * (float)N);  // exact diagonal
    }
}

extern "C" void kernel_launch(void* const* d_in, const int* in_sizes, int n_in,
                              void* d_out, int out_size, void* d_ws, size_t ws_size,
                              hipStream_t stream) {
    const float* x = (const float*)d_in[0];
    float* out     = (float*)d_out;
    _Float16* xT   = (_Float16*)d_ws;                        // 8192*32*2 = 512 KB
    float* sq      = (float*)((char*)d_ws + (size_t)N * CH * sizeof(_Float16)); // +32 KB

    hipMemsetAsync(out, 0, sizeof(float), stream);           // d_out poisoned 0xAA

    prep_kernel<<<N / 256, 256, 0, stream>>>(x, xT, sq);
    dim3 grid(N / BT, N / BT);
    pair_loss_mfma<<<grid, 256, 0, stream>>>(xT, sq, out);
}

// Round 3
// 78.403 us; speedup vs baseline: 1.5502x; 1.0747x over previous
//
#include <hip/hip_runtime.h>

// Single fused kernel: pairwise clipped-linear loss via f16 MFMA Gram tiles.
//   d2_ij = sq_i + sq_j - 2*g_ij ; f(d) = (d-1)(1-d/2) for d<2 else 0
//   out = 0.25 * sum_ij f(d_ij)
// Facts established in R1 (exact fp32 run, absmax 0.0): every off-diagonal
// pair has d2 >= ~40 >> 4, so off-diagonal contributions are all zero and an
// f16 Gram (error ~±0.05) is safe. Diagonal is analytic: 8192*f(0)*0.25 = -2048.
// R2 lesson: ~44.5 us of dur_us is harness reset (256 MB 0xAA fill); minimize
// our portion -> one kernel, triangular grid, no global xT round-trip.

constexpr int N  = 8192;
constexpr int CH = 32;
constexpr int BT = 128;     // block tile edge (128x128 pairs per block)
constexpr int NB = N / BT;  // 64 tile rows -> 64*65/2 = 2080 blocks

typedef _Float16 f16x8  __attribute__((ext_vector_type(8)));
typedef float    f32x16 __attribute__((ext_vector_type(16)));
typedef float    f32x4  __attribute__((ext_vector_type(4)));

__global__ __launch_bounds__(256) void pair_loss_fused(const float* __restrict__ x,
                                                       float* __restrict__ out) {
    // ---- triangular block index: row bi has (NB-bi) blocks, bj in [bi, NB)
    int rem = blockIdx.x, bi = 0;
    while (rem >= NB - bi) { rem -= NB - bi; ++bi; }
    const int bj = bi + rem;
    const int i0 = bi * BT, j0 = bj * BT;
    const bool diagblk = (bi == bj);

    // LDS: f16 tiles in [c8-group][point][8 halves] layout -> both the staging
    // ds_write_b128 and the fragment ds_read_b128 are stride-1 across lanes.
    __shared__ alignas(16) _Float16 T16[2][4][BT][8];   // 16 KB
    __shared__ alignas(16) float    sqs[2][BT];         // 1 KB
    __shared__ float wsum[4];

    const int t    = threadIdx.x;
    const int lane = t & 63, w = t >> 6;

    // ---- stage: threads 0-127 own A-tile point p=t, 128-255 own B-tile p=t-128.
    // Per-c load: a wave's 64 lanes read 64 consecutive floats (coalesced).
    {
        const int p  = t & 127;
        const int ab = t >> 7;
        const int base = (ab ? j0 : i0) + p;
        float v[CH];
        #pragma unroll
        for (int c = 0; c < CH; ++c) v[c] = x[c * N + base];
        float s = 0.f;
        #pragma unroll
        for (int c = 0; c < CH; ++c) s = fmaf(v[c], v[c], s);
        sqs[ab][p] = s;
        #pragma unroll
        for (int c8 = 0; c8 < 4; ++c8) {
            union { _Float16 h[8]; f16x8 v8; } u;
            #pragma unroll
            for (int k = 0; k < 8; ++k) u.h[k] = (_Float16)v[c8 * 8 + k];
            *(f16x8*)&T16[ab][c8][p][0] = u.v8;         // lanes: consecutive 16B
        }
    }
    __syncthreads();

    // ---- 4 waves in 2x2 quadrants of 64x64; each wave: 2x2 tiles of 32x32,
    // 8x mfma_f32_32x32x16_f16 (K=32 = 2 chained steps of 16).
    // A/B frag: lane m=(l&31) holds k = lh*8 + j of the instruction's K=16;
    // our k-halves kh pick c8 = kh*2 + lh.
    const int qr = w >> 1, qc = w & 1;
    const int l31 = lane & 31, lh = lane >> 5;

    f16x8 Af[2][2], Bf[2][2];
    #pragma unroll
    for (int rt = 0; rt < 2; ++rt)
        #pragma unroll
        for (int kh = 0; kh < 2; ++kh) {
            const int c8 = kh * 2 + lh;
            Af[rt][kh] = *(const f16x8*)&T16[0][c8][qr * 64 + rt * 32 + l31][0];
            Bf[rt][kh] = *(const f16x8*)&T16[1][c8][qc * 64 + rt * 32 + l31][0];
        }

    f32x16 acc[2][2];
    #pragma unroll
    for (int rt = 0; rt < 2; ++rt)
        #pragma unroll
        for (int ct = 0; ct < 2; ++ct) {
            #pragma unroll
            for (int r = 0; r < 16; ++r) acc[rt][ct][r] = 0.f;
            acc[rt][ct] = __builtin_amdgcn_mfma_f32_32x32x16_f16(Af[rt][0], Bf[ct][0], acc[rt][ct], 0, 0, 0);
            acc[rt][ct] = __builtin_amdgcn_mfma_f32_32x32x16_f16(Af[rt][1], Bf[ct][1], acc[rt][ct], 0, 0, 0);
        }

    // ---- epilogue: C/D layout col = lane&31, row = (r&3) + 8*(r>>2) + 4*lh.
    float lsum = 0.f;
    #pragma unroll
    for (int rt = 0; rt < 2; ++rt) {
        const int rbase = qr * 64 + rt * 32 + 4 * lh;
        f32x4 sr[4];
        #pragma unroll
        for (int g4 = 0; g4 < 4; ++g4) sr[g4] = *(const f32x4*)&sqs[0][rbase + g4 * 8];
        #pragma unroll
        for (int ct = 0; ct < 2; ++ct) {
            const int cloc = qc * 64 + ct * 32 + l31;
            const float sc = sqs[1][cloc];
            #pragma unroll
            for (int r = 0; r < 16; ++r) {
                float d2 = sr[r >> 2][r & 3] + sc - 2.f * acc[rt][ct][r];
                const int rloc = rbase + (r & 3) + 8 * (r >> 2);
                const bool diag = diagblk && (rloc == cloc);  // exact diag is analytic
                if (d2 < 4.f && !diag) {
                    d2 = fmaxf(d2, 0.f);
                    const float d = sqrtf(d2);
                    lsum += (d - 1.f) * (1.f - 0.5f * d);
                }
            }
        }
    }

    // ---- reduce; almost every block sums to exactly 0 -> skips the atomic
    #pragma unroll
    for (int off = 32; off > 0; off >>= 1) lsum += __shfl_down(lsum, off, 64);
    if ((t & 63) == 0) wsum[t >> 6] = lsum;
    __syncthreads();
    if (t == 0) {
        const float s = wsum[0] + wsum[1] + wsum[2] + wsum[3];
        if (s != 0.f) atomicAdd(out, s * (diagblk ? 0.25f : 0.5f));
        if (blockIdx.x == 0) atomicAdd(out, -0.25f * (float)N);  // exact diagonal sum
    }
}

extern "C" void kernel_launch(void* const* d_in, const int* in_sizes, int n_in,
                              void* d_out, int out_size, void* d_ws, size_t ws_size,
                              hipStream_t stream) {
    const float* x = (const float*)d_in[0];
    float* out     = (float*)d_out;
    hipMemsetAsync(out, 0, sizeof(float), stream);   // d_out poisoned 0xAA
    const int nblocks = NB * (NB + 1) / 2;           // 2080
    pair_loss_fused<<<nblocks, 256, 0, stream>>>(x, out);
}

// Round 4
// 60.241 us; speedup vs baseline: 2.0176x; 1.3015x over previous
//
#include <hip/hip_runtime.h>

// Fused pairwise clipped-linear loss via f16 MFMA Gram tiles.
//   d2_ij = sq_i + sq_j - 2*g_ij ; f(d) = (d-1)(1-d/2) = 1.5d - 0.5d2 - 1 for d<2
//   out = 0.25 * sum_ij f(d_ij)
// R1 (exact fp32, absmax 0.0) established: all off-diagonal pairs have d2 ~ 40+
// >> 4, so f16 Gram error (~±0.05) is safe and almost every block contributes 0.
// Diagonal handled analytically: 8192*f(0)*0.25 = -2048 exactly.
// R4: epilogue is filter-first (1 cmp+branch per 16 accum rows), fast sqrt,
// ballot-gated reduction, closed-form triangular decode, low-VGPR staging.

constexpr int N  = 8192;
constexpr int CH = 32;
constexpr int BT = 128;     // block tile edge
constexpr int NB = N / BT;  // 64 -> 64*65/2 = 2080 triangular blocks

typedef _Float16 f16x8  __attribute__((ext_vector_type(8)));
typedef float    f32x16 __attribute__((ext_vector_type(16)));
typedef float    f32x4  __attribute__((ext_vector_type(4)));

__global__ __launch_bounds__(256, 3) void pair_loss_fused(const float* __restrict__ x,
                                                          float* __restrict__ out) {
    // ---- closed-form triangular decode: u counts blocks from the end
    {
    }
    const int T = NB * (NB + 1) / 2;
    const int u = T - 1 - (int)blockIdx.x;
    int k = (int)((__builtin_amdgcn_sqrtf(8.f * (float)u + 1.f) - 1.f) * 0.5f);
    while (k * (k + 1) / 2 > u) --k;            // fixup for fp rounding (<=1 iter)
    while ((k + 1) * (k + 2) / 2 <= u) ++k;
    const int bi = NB - 1 - k;
    const int bj = NB - 1 - (u - k * (k + 1) / 2);
    const int i0 = bi * BT, j0 = bj * BT;
    const bool diagblk = (bi == bj);

    // LDS: [tile][c8-group][point][8 halves] -> staging ds_write_b128 and
    // fragment ds_read_b128 are both stride-16B across lanes (conflict-free).
    __shared__ alignas(16) _Float16 T16[2][4][BT][8];   // 16 KB
    __shared__ alignas(16) float    sqs[2][BT];         // 1 KB
    __shared__ float wsum[4];

    const int t    = threadIdx.x;
    const int lane = t & 63, w = t >> 6;

    // ---- stage: threads 0-127 -> A point p=t, 128-255 -> B point p=t-128.
    // Per-c8 processing keeps only 8 staging floats live (VGPR pressure).
    {
        const int p  = t & 127;
        const int ab = t >> 7;
        const int base = (ab ? j0 : i0) + p;
        float s = 0.f;
        #pragma unroll
        for (int c8 = 0; c8 < 4; ++c8) {
            float v[8];
            #pragma unroll
            for (int q = 0; q < 8; ++q) v[q] = x[(c8 * 8 + q) * N + base]; // coalesced
            union { _Float16 h[8]; f16x8 v8; } cv;
            #pragma unroll
            for (int q = 0; q < 8; ++q) { s = fmaf(v[q], v[q], s); cv.h[q] = (_Float16)v[q]; }
            *(f16x8*)&T16[ab][c8][p][0] = cv.v8;
        }
        sqs[ab][p] = s;
    }
    __syncthreads();

    // ---- 4 waves = 2x2 quadrants of 64x64; each wave 2x2 tiles of 32x32:
    // 8x mfma_f32_32x32x16_f16 (K=32 = 2 chained steps).
    const int qr = w >> 1, qc = w & 1;
    const int l31 = lane & 31, lh = lane >> 5;

    f16x8 Af[2][2], Bf[2][2];
    #pragma unroll
    for (int rt = 0; rt < 2; ++rt)
        #pragma unroll
        for (int kh = 0; kh < 2; ++kh) {
            const int c8 = kh * 2 + lh;     // lane-half lh holds k = lh*8 + j
            Af[rt][kh] = *(const f16x8*)&T16[0][c8][qr * 64 + rt * 32 + l31][0];
            Bf[rt][kh] = *(const f16x8*)&T16[1][c8][qc * 64 + rt * 32 + l31][0];
        }

    f32x16 acc[2][2];
    #pragma unroll
    for (int rt = 0; rt < 2; ++rt)
        #pragma unroll
        for (int ct = 0; ct < 2; ++ct) {
            #pragma unroll
            for (int r = 0; r < 16; ++r) acc[rt][ct][r] = 0.f;
            acc[rt][ct] = __builtin_amdgcn_mfma_f32_32x32x16_f16(Af[rt][0], Bf[ct][0], acc[rt][ct], 0, 0, 0);
            acc[rt][ct] = __builtin_amdgcn_mfma_f32_32x32x16_f16(Af[rt][1], Bf[ct][1], acc[rt][ct], 0, 0, 0);
        }

    // ---- epilogue. C/D layout: col = lane&31, row = (r&3) + 8*(r>>2) + 4*lh.
    // Filter: d2 < 4  <=>  g - 0.5*sq_r > 0.5*sq_c - 2. One max-reduce + branch
    // per (rt,ct); slow path runs only where a candidate exists (diag tiles).
    float lsum = 0.f;
    #pragma unroll
    for (int rt = 0; rt < 2; ++rt) {
        const int rbase = qr * 64 + rt * 32 + 4 * lh;
        f32x4 sr4[4];
        #pragma unroll
        for (int g4 = 0; g4 < 4; ++g4) sr4[g4] = *(const f32x4*)&sqs[0][rbase + g4 * 8];
        float hsr[16];
        #pragma unroll
        for (int r = 0; r < 16; ++r) hsr[r] = 0.5f * sr4[r >> 2][r & 3];
        #pragma unroll
        for (int ct = 0; ct < 2; ++ct) {
            const int cloc = qc * 64 + ct * 32 + l31;
            const float sc  = sqs[1][cloc];
            const float thr = fmaf(0.5f, sc, -2.f);
            float mx = acc[rt][ct][0] - hsr[0];
            #pragma unroll
            for (int r = 1; r < 16; ++r) mx = fmaxf(mx, acc[rt][ct][r] - hsr[r]);
            if (mx > thr) {                           // almost never (diag tiles only)
                #pragma unroll
                for (int r = 0; r < 16; ++r) {
                    float d2 = sr4[r >> 2][r & 3] + sc - 2.f * acc[rt][ct][r];
                    const int rloc = rbase + (r & 3) + 8 * (r >> 2);
                    if (d2 < 4.f && !(diagblk && rloc == cloc)) {
                        d2 = fmaxf(d2, 0.f);
                        const float d = __builtin_amdgcn_sqrtf(d2);
                        lsum += fmaf(1.5f, d, -fmaf(0.5f, d2, 1.f)); // 1.5d-0.5d2-1
                    }
                }
            }
        }
    }

    // ---- reduce: ballot-gated (2016/2080 blocks skip the shuffle chain)
    if (__ballot(lsum != 0.f)) {
        #pragma unroll
        for (int off = 32; off > 0; off >>= 1) lsum += __shfl_down(lsum, off, 64);
    }
    if (lane == 0) wsum[w] = lsum;
    __syncthreads();
    if (t == 0) {
        const float s = wsum[0] + wsum[1] + wsum[2] + wsum[3];
        if (s != 0.f) atomicAdd(out, s * (diagblk ? 0.25f : 0.5f));
        if (blockIdx.x == 0) atomicAdd(out, -0.25f * (float)N);  // exact diagonal
    }
}

extern "C" void kernel_launch(void* const* d_in, const int* in_sizes, int n_in,
                              void* d_out, int out_size, void* d_ws, size_t ws_size,
                              hipStream_t stream) {
    const float* x = (const float*)d_in[0];
    float* out     = (float*)d_out;
    hipMemsetAsync(out, 0, sizeof(float), stream);   // d_out poisoned 0xAA
    pair_loss_fused<<<NB * (NB + 1) / 2, 256, 0, stream>>>(x, out);
}